// Round 8
// baseline (216.753 us; speedup 1.0000x reference)
//
#include <hip/hip_runtime.h>
#include <hip/hip_fp16.h>

#define NEG_SLOPE 0.2f
#define DB 128       // dst nodes per bucket
#define NB_MAX 512   // max buckets (N <= 65536)
#define EPB 4096     // edges per block in partition path
#define CAP 8192     // fixed capacity per bucket segment (mean load ~4092)

// ============ merged: GEMM1+scores1 (blocks [0,G1)) ∥ edge partition (rest) ============
// LDS capped at 32 KB (fp16 staging) => 5 blocks/CU instead of 2.
__global__ __launch_bounds__(256) void k_g1p(
    const float* __restrict__ x, const float* __restrict__ W,
    const float* __restrict__ a_src, const float* __restrict__ a_dst,
    __half* __restrict__ h1, float* __restrict__ es, float* __restrict__ ed, int N,
    const int* __restrict__ srcv, const int* __restrict__ dstv,
    int* __restrict__ gcur, int* __restrict__ ebuf, int E, int G1) {
  __shared__ __align__(16) char smem[32768];
  const int t = threadIdx.x;

  if ((int)blockIdx.x < G1) {
    // ---------------- GEMM1 + fused scores1 (fp16 LDS, fp32 accumulate) ----------------
    __half* sXT = (__half*)smem;            // [k][row] 128x64 halves, 16 KB
    __half* sW  = (__half*)(smem + 16384);  // [k][col] 128x64 halves, 16 KB
    const int r0 = blockIdx.x * 64;
    {
      const float4* Wp = (const float4*)W;
#pragma unroll
      for (int i = 0; i < 8; ++i) {
        float4 v = Wp[t + i * 256];
        int fi = (t + i * 256) * 4;  // flat float idx; k = fi>>6, col = fi&63
        union { __half2 h2[2]; float2 f; } u;
        u.h2[0] = __float22half2_rn(make_float2(v.x, v.y));
        u.h2[1] = __float22half2_rn(make_float2(v.z, v.w));
        *(float2*)(sW + fi) = u.f;  // same flat layout [k][col]
      }
    }
    {
      int r = t & 63;
      int kq = t >> 6;
      int gr = r0 + r;
      bool ok = gr < N;
      const float* xr = x + (size_t)gr * 128;
#pragma unroll
      for (int p = 0; p < 8; ++p) {
        int k = (kq + p * 4) * 4;
        float4 v = ok ? *(const float4*)(xr + k) : make_float4(0.f, 0.f, 0.f, 0.f);
        sXT[(k + 0) * 64 + r] = __float2half(v.x);
        sXT[(k + 1) * 64 + r] = __float2half(v.y);
        sXT[(k + 2) * 64 + r] = __float2half(v.z);
        sXT[(k + 3) * 64 + r] = __float2half(v.w);
      }
    }
    __syncthreads();

    const int tx = t & 15, ty = t >> 4;
    float4 acc0 = make_float4(0.f, 0.f, 0.f, 0.f);
    float4 acc1 = acc0, acc2 = acc0, acc3 = acc0;
#pragma unroll 4
    for (int k = 0; k < 128; ++k) {
      const __half2* ap = (const __half2*)(sXT + k * 64 + ty * 4);
      const __half2* bp = (const __half2*)(sW + k * 64 + tx * 4);
      float2 a01 = __half22float2(ap[0]);
      float2 a23 = __half22float2(ap[1]);
      float2 b01 = __half22float2(bp[0]);
      float2 b23 = __half22float2(bp[1]);
      acc0.x += a01.x * b01.x; acc0.y += a01.x * b01.y; acc0.z += a01.x * b23.x; acc0.w += a01.x * b23.y;
      acc1.x += a01.y * b01.x; acc1.y += a01.y * b01.y; acc1.z += a01.y * b23.x; acc1.w += a01.y * b23.y;
      acc2.x += a23.x * b01.x; acc2.y += a23.x * b01.y; acc2.z += a23.x * b23.x; acc2.w += a23.x * b23.y;
      acc3.x += a23.y * b01.x; acc3.y += a23.y * b01.y; acc3.z += a23.y * b23.x; acc3.w += a23.y * b23.y;
    }

    float4 accs[4] = {acc0, acc1, acc2, acc3};
#pragma unroll
    for (int i = 0; i < 4; ++i) {
      int gr = r0 + ty * 4 + i;
      if (gr < N) {
        union { __half2 h[2]; float2 f; } u;
        u.h[0] = __float22half2_rn(make_float2(accs[i].x, accs[i].y));
        u.h[1] = __float22half2_rn(make_float2(accs[i].z, accs[i].w));
        *(float2*)(h1 + (size_t)gr * 64 + tx * 4) = u.f;
      }
    }

    float4 asv = *(const float4*)(a_src + tx * 4);
    float4 adv = *(const float4*)(a_dst + tx * 4);
    float esp[4], edp[4];
#pragma unroll
    for (int i = 0; i < 4; ++i) {
      esp[i] = accs[i].x * asv.x + accs[i].y * asv.y + accs[i].z * asv.z + accs[i].w * asv.w;
      edp[i] = accs[i].x * adv.x + accs[i].y * adv.y + accs[i].z * adv.z + accs[i].w * adv.w;
    }
#pragma unroll
    for (int off = 1; off <= 4; off <<= 1) {
#pragma unroll
      for (int i = 0; i < 4; ++i) {
        esp[i] += __shfl_xor(esp[i], off);
        edp[i] += __shfl_xor(edp[i], off);
      }
    }
    if ((tx & 7) == 0) {
      int hh = tx >> 3;
#pragma unroll
      for (int i = 0; i < 4; ++i) {
        int gr = r0 + ty * 4 + i;
        if (gr < N) {
          es[gr * 2 + hh] = esp[i];
          ed[gr * 2 + hh] = edp[i];
        }
      }
    }
  } else {
    // ---------------- edge partition into fixed-cap bucket segments ----------------
    int* sh    = (int*)smem;           // 512 ints
    int* lbase = (int*)(smem + 2048);  // 512 ints
    sh[t] = 0; sh[t + 256] = 0;
    __syncthreads();
    int base = (blockIdx.x - G1) * EPB;
    int dd[16];
#pragma unroll
    for (int i = 0; i < 16; ++i) {
      int e = base + i * 256 + t;
      dd[i] = (e < E) ? dstv[e] : -1;
      if (dd[i] >= 0) atomicAdd(&sh[dd[i] >> 7], 1);
    }
    __syncthreads();
#pragma unroll
    for (int i = 0; i < 2; ++i) {
      int b = t + 256 * i;
      int c = sh[b];
      lbase[b] = c ? (b * CAP + atomicAdd(&gcur[b], c)) : 0;
      sh[b] = 0;  // becomes local cursor
    }
    __syncthreads();
#pragma unroll
    for (int i = 0; i < 16; ++i) {
      if (dd[i] >= 0) {
        int e = base + i * 256 + t;
        int b = dd[i] >> 7;
        int r = atomicAdd(&sh[b], 1);
        ebuf[lbase[b] + r] = srcv[e] | ((dd[i] & 127) << 16);
      }
    }
  }
}

// Phase 2: per-bucket local counting sort -> rowbeg/rowend + col(u16)
__global__ __launch_bounds__(256) void k_csr(const int* __restrict__ gcur,
                                             const int* __restrict__ ebuf,
                                             int* __restrict__ rowbeg,
                                             int* __restrict__ rowend,
                                             unsigned short* __restrict__ col, int N) {
  int b = blockIdx.x;
  int cnt = gcur[b];
  int base = b * CAP;
  int dbase = b * DB;
  __shared__ int dh[DB];
  __shared__ int sc[DB];
  int t = threadIdx.x;
  if (t < DB) dh[t] = 0;
  __syncthreads();
  for (int j = t; j < cnt; j += 256) {
    int p = ebuf[base + j];
    atomicAdd(&dh[p >> 16], 1);
  }
  __syncthreads();
  int v = 0;
  if (t < DB) { v = dh[t]; sc[t] = v; }
  __syncthreads();
  for (int off = 1; off < DB; off <<= 1) {
    int u = 0;
    if (t < DB && t >= off) u = sc[t - off];
    __syncthreads();
    if (t < DB) sc[t] += u;
    __syncthreads();
  }
  if (t < DB) {
    int excl = sc[t] - v;
    int d = dbase + t;
    if (d < N) {
      rowbeg[d] = base + excl;
      rowend[d] = base + excl + v;
    }
    dh[t] = base + excl;
  }
  __syncthreads();
  for (int j = t; j < cnt; j += 256) {
    int p = ebuf[base + j];
    int r = atomicAdd(&dh[p >> 16], 1);
    col[r] = (unsigned short)(p & 0xFFFF);
  }
}

// ===== agg layer 1 FUSED with GEMM2+scores2 =====
// One wave per dst node: softmax-aggregate (8 groups x 8 lanes), then the wave
// computes hL2[d] = relu(out1row)@W2 + es2/ed2 in-register. out1 never hits memory.
__global__ __launch_bounds__(256) void k_agg1(
    const int* __restrict__ rowbeg, const int* __restrict__ rowend,
    const unsigned short* __restrict__ col,
    const __half* __restrict__ h1,
    const float* __restrict__ es, const float* __restrict__ ed,
    const float* __restrict__ b1,
    const float* __restrict__ W2,
    const float* __restrict__ a_src2, const float* __restrict__ a_dst2,
    __half* __restrict__ hL2, float* __restrict__ es2, float* __restrict__ ed2,
    int N) {
  __shared__ float sW2[64 * 32];  // 8 KB
  __shared__ float sRow[4 * 64];  // per-wave row broadcast, 1 KB
  const int t = threadIdx.x;
  {
    const float4* Wp = (const float4*)W2;
    float4* sp = (float4*)sW2;
    sp[t] = Wp[t];
    sp[t + 256] = Wp[t + 256];
  }
  __syncthreads();

  int d = (blockIdx.x * 256 + t) >> 6;
  int lane = t & 63;
  int wid = t >> 6;
  if (d >= N) return;

  int g = lane >> 3;   // edge group 0..7
  int q = lane & 7;    // channel octet 0..7
  int ch = q * 8;
  int hh = q >> 2;     // head
  float edv = ed[d * 2 + hh];

  float a0 = 0.f, a1 = 0.f, a2 = 0.f, a3 = 0.f, a4 = 0.f, a5 = 0.f, a6 = 0.f, a7 = 0.f;
  float wsum = 0.f;

  if (g == 0) {  // self-loop
    float v = es[d * 2 + hh] + edv;
    v = v > 0.f ? v : NEG_SLOPE * v;
    float w = __expf(v);
    float4 raw = *(const float4*)(h1 + (size_t)d * 64 + ch);
    const __half2* p2 = (const __half2*)&raw;
    float2 f0 = __half22float2(p2[0]), f1 = __half22float2(p2[1]);
    float2 f2 = __half22float2(p2[2]), f3 = __half22float2(p2[3]);
    a0 = w * f0.x; a1 = w * f0.y; a2 = w * f1.x; a3 = w * f1.y;
    a4 = w * f2.x; a5 = w * f2.y; a6 = w * f3.x; a7 = w * f3.y;
    wsum = w;
  }

  int beg = rowbeg[d], end = rowend[d];
  for (int j = beg + g; j < end; j += 8) {
    int s = col[j];
    float vv = es[s * 2 + hh] + edv;
    vv = vv > 0.f ? vv : NEG_SLOPE * vv;
    float w = __expf(vv);
    float4 raw = *(const float4*)(h1 + (size_t)s * 64 + ch);
    const __half2* p2 = (const __half2*)&raw;
    float2 f0 = __half22float2(p2[0]), f1 = __half22float2(p2[1]);
    float2 f2 = __half22float2(p2[2]), f3 = __half22float2(p2[3]);
    a0 += w * f0.x; a1 += w * f0.y; a2 += w * f1.x; a3 += w * f1.y;
    a4 += w * f2.x; a5 += w * f2.y; a6 += w * f3.x; a7 += w * f3.y;
    wsum += w;
  }

#pragma unroll
  for (int off = 8; off <= 32; off <<= 1) {
    a0 += __shfl_xor(a0, off); a1 += __shfl_xor(a1, off);
    a2 += __shfl_xor(a2, off); a3 += __shfl_xor(a3, off);
    a4 += __shfl_xor(a4, off); a5 += __shfl_xor(a5, off);
    a6 += __shfl_xor(a6, off); a7 += __shfl_xor(a7, off);
    wsum += __shfl_xor(wsum, off);
  }

  // out1 row (bias + relu) -> per-wave LDS broadcast (wave-internal, no barrier)
  float inv = 1.f / (wsum + 1e-16f);
  if (g == 0) {
    const float4 bv0 = *(const float4*)(b1 + ch);
    const float4 bv1 = *(const float4*)(b1 + ch + 4);
    float4 o0, o1;
    o0.x = fmaxf(a0 * inv + bv0.x, 0.f); o0.y = fmaxf(a1 * inv + bv0.y, 0.f);
    o0.z = fmaxf(a2 * inv + bv0.z, 0.f); o0.w = fmaxf(a3 * inv + bv0.w, 0.f);
    o1.x = fmaxf(a4 * inv + bv1.x, 0.f); o1.y = fmaxf(a5 * inv + bv1.y, 0.f);
    o1.z = fmaxf(a6 * inv + bv1.z, 0.f); o1.w = fmaxf(a7 * inv + bv1.w, 0.f);
    *(float4*)(sRow + wid * 64 + ch) = o0;
    *(float4*)(sRow + wid * 64 + ch + 4) = o1;
  }

  // matvec: hL2[d][c] = row @ W2[:,c]; lanes: c = lane&31, k-half = lane>>5
  int c = lane & 31, kh = lane >> 5;
  const float* rp = sRow + wid * 64 + kh * 32;
  const float* wp = sW2 + (kh * 32) * 32 + c;
  float hv = 0.f;
#pragma unroll
  for (int k2 = 0; k2 < 32; ++k2) hv += rp[k2] * wp[k2 * 32];
  hv += __shfl_xor(hv, 32);  // lanes 0..31 (dup 32..63) hold hL2[d][c]

  float e_s = hv * a_src2[c];
  float e_d = hv * a_dst2[c];
#pragma unroll
  for (int off = 1; off <= 16; off <<= 1) {
    e_s += __shfl_xor(e_s, off);
    e_d += __shfl_xor(e_d, off);
  }
  if (lane == 0) { es2[d] = e_s; ed2[d] = e_d; }

  float hv2 = __shfl_xor(hv, 1);
  if (lane < 32 && !(lane & 1)) {
    *(__half2*)(hL2 + (size_t)d * 32 + c) = __float22half2_rn(make_float2(hv, hv2));
  }
}

// -------- agg layer 2: one wave per dst; 16 groups x 4 lanes --------
__global__ __launch_bounds__(256) void k_agg2(const int* __restrict__ rowbeg,
                                              const int* __restrict__ rowend,
                                              const unsigned short* __restrict__ col,
                                              const __half* __restrict__ hL2,
                                              const float* __restrict__ es,
                                              const float* __restrict__ ed,
                                              const float* __restrict__ bias,
                                              float* __restrict__ out, int N) {
  int d = (blockIdx.x * blockDim.x + threadIdx.x) >> 6;
  int lane = threadIdx.x & 63;
  if (d >= N) return;
  int g = lane >> 2;   // edge group 0..15
  int q = lane & 3;    // channel octet 0..3
  int ch = q * 8;
  float edv = ed[d];

  float a0 = 0.f, a1 = 0.f, a2 = 0.f, a3 = 0.f, a4 = 0.f, a5 = 0.f, a6 = 0.f, a7 = 0.f;
  float wsum = 0.f;

  if (g == 0) {
    float v = es[d] + edv;
    v = v > 0.f ? v : NEG_SLOPE * v;
    float w = __expf(v);
    float4 raw = *(const float4*)(hL2 + (size_t)d * 32 + ch);
    const __half2* p2 = (const __half2*)&raw;
    float2 f0 = __half22float2(p2[0]), f1 = __half22float2(p2[1]);
    float2 f2 = __half22float2(p2[2]), f3 = __half22float2(p2[3]);
    a0 = w * f0.x; a1 = w * f0.y; a2 = w * f1.x; a3 = w * f1.y;
    a4 = w * f2.x; a5 = w * f2.y; a6 = w * f3.x; a7 = w * f3.y;
    wsum = w;
  }

  int beg = rowbeg[d], end = rowend[d];
  for (int j = beg + g; j < end; j += 16) {
    int s = col[j];
    float vv = es[s] + edv;
    vv = vv > 0.f ? vv : NEG_SLOPE * vv;
    float w = __expf(vv);
    float4 raw = *(const float4*)(hL2 + (size_t)s * 32 + ch);
    const __half2* p2 = (const __half2*)&raw;
    float2 f0 = __half22float2(p2[0]), f1 = __half22float2(p2[1]);
    float2 f2 = __half22float2(p2[2]), f3 = __half22float2(p2[3]);
    a0 += w * f0.x; a1 += w * f0.y; a2 += w * f1.x; a3 += w * f1.y;
    a4 += w * f2.x; a5 += w * f2.y; a6 += w * f3.x; a7 += w * f3.y;
    wsum += w;
  }

#pragma unroll
  for (int off = 4; off <= 32; off <<= 1) {
    a0 += __shfl_xor(a0, off); a1 += __shfl_xor(a1, off);
    a2 += __shfl_xor(a2, off); a3 += __shfl_xor(a3, off);
    a4 += __shfl_xor(a4, off); a5 += __shfl_xor(a5, off);
    a6 += __shfl_xor(a6, off); a7 += __shfl_xor(a7, off);
    wsum += __shfl_xor(wsum, off);
  }

  if (g == 0) {
    float inv = 1.f / (wsum + 1e-16f);
    const float4 bv0 = *(const float4*)(bias + ch);
    const float4 bv1 = *(const float4*)(bias + ch + 4);
    float4 o0, o1;
    o0.x = a0 * inv + bv0.x; o0.y = a1 * inv + bv0.y;
    o0.z = a2 * inv + bv0.z; o0.w = a3 * inv + bv0.w;
    o1.x = a4 * inv + bv1.x; o1.y = a5 * inv + bv1.y;
    o1.z = a6 * inv + bv1.z; o1.w = a7 * inv + bv1.w;
    *(float4*)(out + (size_t)d * 32 + ch) = o0;
    *(float4*)(out + (size_t)d * 32 + ch + 4) = o1;
  }
}

extern "C" void kernel_launch(void* const* d_in, const int* in_sizes, int n_in,
                              void* d_out, int out_size, void* d_ws, size_t ws_size,
                              hipStream_t stream) {
  const float* x      = (const float*)d_in[0];
  const int*   ei     = (const int*)d_in[1];
  const float* W1     = (const float*)d_in[2];
  const float* a_src1 = (const float*)d_in[3];
  const float* a_dst1 = (const float*)d_in[4];
  const float* b1     = (const float*)d_in[5];
  const float* W2     = (const float*)d_in[6];
  const float* a_src2 = (const float*)d_in[7];
  const float* a_dst2 = (const float*)d_in[8];
  const float* b2     = (const float*)d_in[9];
  float* out = (float*)d_out;

  const int N = in_sizes[0] / 128;
  const int E = in_sizes[1] / 2;
  const int NB = (N + DB - 1) / DB;
  const int* srcv = ei;
  const int* dstv = ei + E;

  char* base = (char*)d_ws;
  size_t off = 0;
  auto carve = [&](size_t bytes) {
    void* p = base + off;
    off += (bytes + 15) & ~(size_t)15;
    return p;
  };
  __half* h1     = (__half*)carve((size_t)N * 64 * 2);
  float*  es1    = (float*)carve((size_t)N * 2 * 4);
  float*  ed1    = (float*)carve((size_t)N * 2 * 4);
  __half* hL2    = (__half*)carve((size_t)N * 32 * 2);
  float*  es2    = (float*)carve((size_t)N * 4);
  float*  ed2    = (float*)carve((size_t)N * 4);
  int*    gcur   = (int*)carve((size_t)NB_MAX * 4);
  int*    rowbeg = (int*)carve((size_t)N * 4);
  int*    rowend = (int*)carve((size_t)N * 4);
  unsigned short* col = (unsigned short*)carve((size_t)NB * CAP * 2);
  int*    ebuf   = (int*)carve((size_t)NB * CAP * 4);

  const int pblocks = (E + EPB - 1) / EPB;
  const int G1 = (N + 63) / 64;

  hipMemsetAsync(gcur, 0, (size_t)NB_MAX * sizeof(int), stream);

  // ---- gemm1+scores1 ∥ edge partition (independent) ----
  k_g1p<<<G1 + pblocks, 256, 0, stream>>>(x, W1, a_src1, a_dst1, h1, es1, ed1, N,
                                          srcv, dstv, gcur, ebuf, E, G1);
  // ---- per-bucket CSR finalize ----
  k_csr<<<NB, 256, 0, stream>>>(gcur, ebuf, rowbeg, rowend, col, N);

  // ---- layer-1 aggregate + fused GEMM2/scores2 ----
  k_agg1<<<((size_t)N * 64 + 255) / 256, 256, 0, stream>>>(
      rowbeg, rowend, col, h1, es1, ed1, b1, W2, a_src2, a_dst2, hL2, es2, ed2, N);

  // ---- layer-2 aggregate ----
  k_agg2<<<((size_t)N * 64 + 255) / 256, 256, 0, stream>>>(rowbeg, rowend, col, hL2, es2, ed2, b2, out, N);
}

// Round 9
// 210.150 us; speedup vs baseline: 1.0314x; 1.0314x over previous
//
#include <hip/hip_runtime.h>
#include <hip/hip_fp16.h>

#define NEG_SLOPE 0.2f
#define DB 128       // dst nodes per bucket
#define NB_MAX 512   // max buckets (N <= 65536)
#define EPB 4096     // edges per block in partition path
#define CAP 8192     // fixed capacity per bucket segment (mean load ~4092)

// ============ merged: GEMM1+scores1 (blocks [0,G1)) ∥ edge partition (rest) ============
// LDS 32 KB (fp16 staging) => ~5 blocks/CU.
__global__ __launch_bounds__(256) void k_g1p(
    const float* __restrict__ x, const float* __restrict__ W,
    const float* __restrict__ a_src, const float* __restrict__ a_dst,
    __half* __restrict__ h1, float* __restrict__ es, float* __restrict__ ed, int N,
    const int* __restrict__ srcv, const int* __restrict__ dstv,
    int* __restrict__ gcur, int* __restrict__ ebuf, int E, int G1) {
  __shared__ __align__(16) char smem[32768];
  const int t = threadIdx.x;

  if ((int)blockIdx.x < G1) {
    // ---------------- GEMM1 + fused scores1 (fp16 LDS, fp32 accumulate) ----------------
    __half* sXT = (__half*)smem;            // [k][row] 128x64 halves, 16 KB
    __half* sW  = (__half*)(smem + 16384);  // [k][col] 128x64 halves, 16 KB
    const int r0 = blockIdx.x * 64;
    {
      const float4* Wp = (const float4*)W;
#pragma unroll
      for (int i = 0; i < 8; ++i) {
        float4 v = Wp[t + i * 256];
        int fi = (t + i * 256) * 4;
        union { __half2 h2[2]; float2 f; } u;
        u.h2[0] = __float22half2_rn(make_float2(v.x, v.y));
        u.h2[1] = __float22half2_rn(make_float2(v.z, v.w));
        *(float2*)(sW + fi) = u.f;
      }
    }
    {
      int r = t & 63;
      int kq = t >> 6;
      int gr = r0 + r;
      bool ok = gr < N;
      const float* xr = x + (size_t)gr * 128;
#pragma unroll
      for (int p = 0; p < 8; ++p) {
        int k = (kq + p * 4) * 4;
        float4 v = ok ? *(const float4*)(xr + k) : make_float4(0.f, 0.f, 0.f, 0.f);
        sXT[(k + 0) * 64 + r] = __float2half(v.x);
        sXT[(k + 1) * 64 + r] = __float2half(v.y);
        sXT[(k + 2) * 64 + r] = __float2half(v.z);
        sXT[(k + 3) * 64 + r] = __float2half(v.w);
      }
    }
    __syncthreads();

    const int tx = t & 15, ty = t >> 4;
    float4 acc0 = make_float4(0.f, 0.f, 0.f, 0.f);
    float4 acc1 = acc0, acc2 = acc0, acc3 = acc0;
#pragma unroll 4
    for (int k = 0; k < 128; ++k) {
      const __half2* ap = (const __half2*)(sXT + k * 64 + ty * 4);
      const __half2* bp = (const __half2*)(sW + k * 64 + tx * 4);
      float2 a01 = __half22float2(ap[0]);
      float2 a23 = __half22float2(ap[1]);
      float2 b01 = __half22float2(bp[0]);
      float2 b23 = __half22float2(bp[1]);
      acc0.x += a01.x * b01.x; acc0.y += a01.x * b01.y; acc0.z += a01.x * b23.x; acc0.w += a01.x * b23.y;
      acc1.x += a01.y * b01.x; acc1.y += a01.y * b01.y; acc1.z += a01.y * b23.x; acc1.w += a01.y * b23.y;
      acc2.x += a23.x * b01.x; acc2.y += a23.x * b01.y; acc2.z += a23.x * b23.x; acc2.w += a23.x * b23.y;
      acc3.x += a23.y * b01.x; acc3.y += a23.y * b01.y; acc3.z += a23.y * b23.x; acc3.w += a23.y * b23.y;
    }

    float4 accs[4] = {acc0, acc1, acc2, acc3};
#pragma unroll
    for (int i = 0; i < 4; ++i) {
      int gr = r0 + ty * 4 + i;
      if (gr < N) {
        union { __half2 h[2]; float2 f; } u;
        u.h[0] = __float22half2_rn(make_float2(accs[i].x, accs[i].y));
        u.h[1] = __float22half2_rn(make_float2(accs[i].z, accs[i].w));
        *(float2*)(h1 + (size_t)gr * 64 + tx * 4) = u.f;
      }
    }

    float4 asv = *(const float4*)(a_src + tx * 4);
    float4 adv = *(const float4*)(a_dst + tx * 4);
    float esp[4], edp[4];
#pragma unroll
    for (int i = 0; i < 4; ++i) {
      esp[i] = accs[i].x * asv.x + accs[i].y * asv.y + accs[i].z * asv.z + accs[i].w * asv.w;
      edp[i] = accs[i].x * adv.x + accs[i].y * adv.y + accs[i].z * adv.z + accs[i].w * adv.w;
    }
#pragma unroll
    for (int off = 1; off <= 4; off <<= 1) {
#pragma unroll
      for (int i = 0; i < 4; ++i) {
        esp[i] += __shfl_xor(esp[i], off);
        edp[i] += __shfl_xor(edp[i], off);
      }
    }
    if ((tx & 7) == 0) {
      int hh = tx >> 3;
#pragma unroll
      for (int i = 0; i < 4; ++i) {
        int gr = r0 + ty * 4 + i;
        if (gr < N) {
          es[gr * 2 + hh] = esp[i];
          ed[gr * 2 + hh] = edp[i];
        }
      }
    }
  } else {
    // ---------------- edge partition into fixed-cap bucket segments ----------------
    int* sh    = (int*)smem;           // 512 ints
    int* lbase = (int*)(smem + 2048);  // 512 ints
    sh[t] = 0; sh[t + 256] = 0;
    __syncthreads();
    int base = (blockIdx.x - G1) * EPB;
    int dd[16];
#pragma unroll
    for (int i = 0; i < 16; ++i) {
      int e = base + i * 256 + t;
      dd[i] = (e < E) ? dstv[e] : -1;
      if (dd[i] >= 0) atomicAdd(&sh[dd[i] >> 7], 1);
    }
    __syncthreads();
#pragma unroll
    for (int i = 0; i < 2; ++i) {
      int b = t + 256 * i;
      int c = sh[b];
      lbase[b] = c ? (b * CAP + atomicAdd(&gcur[b], c)) : 0;
      sh[b] = 0;  // becomes local cursor
    }
    __syncthreads();
#pragma unroll
    for (int i = 0; i < 16; ++i) {
      if (dd[i] >= 0) {
        int e = base + i * 256 + t;
        int b = dd[i] >> 7;
        int r = atomicAdd(&sh[b], 1);
        ebuf[lbase[b] + r] = srcv[e] | ((dd[i] & 127) << 16);
      }
    }
  }
}

// Phase 2: per-bucket local counting sort -> rowbeg/rowend + col(u16)
__global__ __launch_bounds__(256) void k_csr(const int* __restrict__ gcur,
                                             const int* __restrict__ ebuf,
                                             int* __restrict__ rowbeg,
                                             int* __restrict__ rowend,
                                             unsigned short* __restrict__ col, int N) {
  int b = blockIdx.x;
  int cnt = gcur[b];
  int base = b * CAP;
  int dbase = b * DB;
  __shared__ int dh[DB];
  __shared__ int sc[DB];
  int t = threadIdx.x;
  if (t < DB) dh[t] = 0;
  __syncthreads();
  for (int j = t; j < cnt; j += 256) {
    int p = ebuf[base + j];
    atomicAdd(&dh[p >> 16], 1);
  }
  __syncthreads();
  int v = 0;
  if (t < DB) { v = dh[t]; sc[t] = v; }
  __syncthreads();
  for (int off = 1; off < DB; off <<= 1) {
    int u = 0;
    if (t < DB && t >= off) u = sc[t - off];
    __syncthreads();
    if (t < DB) sc[t] += u;
    __syncthreads();
  }
  if (t < DB) {
    int excl = sc[t] - v;
    int d = dbase + t;
    if (d < N) {
      rowbeg[d] = base + excl;
      rowend[d] = base + excl + v;
    }
    dh[t] = base + excl;
  }
  __syncthreads();
  for (int j = t; j < cnt; j += 256) {
    int p = ebuf[base + j];
    int r = atomicAdd(&dh[p >> 16], 1);
    col[r] = (unsigned short)(p & 0xFFFF);
  }
}

// -------- agg layer 1: one wave per dst; 8 groups x 8 lanes; 8 edges in flight --------
__global__ __launch_bounds__(256) void k_agg1(const int* __restrict__ rowbeg,
                                              const int* __restrict__ rowend,
                                              const unsigned short* __restrict__ col,
                                              const __half* __restrict__ h1,
                                              const float* __restrict__ es,
                                              const float* __restrict__ ed,
                                              const float* __restrict__ bias,
                                              float* __restrict__ out1, int N) {
  int d = (blockIdx.x * blockDim.x + threadIdx.x) >> 6;
  int lane = threadIdx.x & 63;
  if (d >= N) return;
  int g = lane >> 3;   // edge group 0..7
  int q = lane & 7;    // channel octet 0..7
  int ch = q * 8;
  int hh = q >> 2;     // head
  float edv = ed[d * 2 + hh];

  float a0 = 0.f, a1 = 0.f, a2 = 0.f, a3 = 0.f, a4 = 0.f, a5 = 0.f, a6 = 0.f, a7 = 0.f;
  float wsum = 0.f;

  if (g == 0) {  // self-loop
    float v = es[d * 2 + hh] + edv;
    v = v > 0.f ? v : NEG_SLOPE * v;
    float w = __expf(v);
    float4 raw = *(const float4*)(h1 + (size_t)d * 64 + ch);
    const __half2* p2 = (const __half2*)&raw;
    float2 f0 = __half22float2(p2[0]), f1 = __half22float2(p2[1]);
    float2 f2 = __half22float2(p2[2]), f3 = __half22float2(p2[3]);
    a0 = w * f0.x; a1 = w * f0.y; a2 = w * f1.x; a3 = w * f1.y;
    a4 = w * f2.x; a5 = w * f2.y; a6 = w * f3.x; a7 = w * f3.y;
    wsum = w;
  }

  int beg = rowbeg[d], end = rowend[d];
  for (int j = beg + g; j < end; j += 8) {
    int s = col[j];
    float vv = es[s * 2 + hh] + edv;
    vv = vv > 0.f ? vv : NEG_SLOPE * vv;
    float w = __expf(vv);
    float4 raw = *(const float4*)(h1 + (size_t)s * 64 + ch);
    const __half2* p2 = (const __half2*)&raw;
    float2 f0 = __half22float2(p2[0]), f1 = __half22float2(p2[1]);
    float2 f2 = __half22float2(p2[2]), f3 = __half22float2(p2[3]);
    a0 += w * f0.x; a1 += w * f0.y; a2 += w * f1.x; a3 += w * f1.y;
    a4 += w * f2.x; a5 += w * f2.y; a6 += w * f3.x; a7 += w * f3.y;
    wsum += w;
  }

#pragma unroll
  for (int off = 8; off <= 32; off <<= 1) {
    a0 += __shfl_xor(a0, off); a1 += __shfl_xor(a1, off);
    a2 += __shfl_xor(a2, off); a3 += __shfl_xor(a3, off);
    a4 += __shfl_xor(a4, off); a5 += __shfl_xor(a5, off);
    a6 += __shfl_xor(a6, off); a7 += __shfl_xor(a7, off);
    wsum += __shfl_xor(wsum, off);
  }

  if (g == 0) {
    float inv = 1.f / (wsum + 1e-16f);
    const float4 bv0 = *(const float4*)(bias + ch);
    const float4 bv1 = *(const float4*)(bias + ch + 4);
    float4 o0, o1;
    o0.x = a0 * inv + bv0.x; o0.y = a1 * inv + bv0.y;
    o0.z = a2 * inv + bv0.z; o0.w = a3 * inv + bv0.w;
    o1.x = a4 * inv + bv1.x; o1.y = a5 * inv + bv1.y;
    o1.z = a6 * inv + bv1.z; o1.w = a7 * inv + bv1.w;
    *(float4*)(out1 + (size_t)d * 64 + ch) = o0;
    *(float4*)(out1 + (size_t)d * 64 + ch + 4) = o1;
  }
}

// ======== GEMM2 + fused scores2: hL2(fp16) = relu(out1)@W2 ; es2/ed2 ========
__global__ __launch_bounds__(256) void k_gemm2(const float* __restrict__ out1,
                                               const float* __restrict__ W,
                                               const float* __restrict__ a_src,
                                               const float* __restrict__ a_dst,
                                               __half* __restrict__ hL2,
                                               float* __restrict__ es,
                                               float* __restrict__ ed, int N) {
  __shared__ float sXT[64 * 128];
  __shared__ float sW[64 * 32];
  const int t = threadIdx.x;
  const int r0 = blockIdx.x * 128;

  {
    const float4* Wp = (const float4*)W;
    float4* sWp = (float4*)sW;
#pragma unroll
    for (int i = 0; i < 2; ++i) sWp[t + i * 256] = Wp[t + i * 256];
  }
  {
    int r = t & 127;
    int kq = t >> 7;
    int gr = r0 + r;
    bool ok = gr < N;
    const float* xr = out1 + (size_t)gr * 64;
#pragma unroll
    for (int p = 0; p < 8; ++p) {
      int k = (kq + p * 2) * 4;
      float4 v = ok ? *(const float4*)(xr + k) : make_float4(0.f, 0.f, 0.f, 0.f);
      sXT[(k + 0) * 128 + r] = fmaxf(v.x, 0.f);
      sXT[(k + 1) * 128 + r] = fmaxf(v.y, 0.f);
      sXT[(k + 2) * 128 + r] = fmaxf(v.z, 0.f);
      sXT[(k + 3) * 128 + r] = fmaxf(v.w, 0.f);
    }
  }
  __syncthreads();

  const int tx = t & 7, ty = t >> 3;
  float4 acc0 = make_float4(0.f, 0.f, 0.f, 0.f);
  float4 acc1 = acc0, acc2 = acc0, acc3 = acc0;
#pragma unroll 8
  for (int k = 0; k < 64; ++k) {
    float4 av = *(const float4*)(sXT + k * 128 + ty * 4);
    float4 bv = *(const float4*)(sW + k * 32 + tx * 4);
    acc0.x += av.x * bv.x; acc0.y += av.x * bv.y; acc0.z += av.x * bv.z; acc0.w += av.x * bv.w;
    acc1.x += av.y * bv.x; acc1.y += av.y * bv.y; acc1.z += av.y * bv.z; acc1.w += av.y * bv.w;
    acc2.x += av.z * bv.x; acc2.y += av.z * bv.y; acc2.z += av.z * bv.z; acc2.w += av.z * bv.w;
    acc3.x += av.w * bv.x; acc3.y += av.w * bv.y; acc3.z += av.w * bv.z; acc3.w += av.w * bv.w;
  }

  float4 accs[4] = {acc0, acc1, acc2, acc3};
#pragma unroll
  for (int i = 0; i < 4; ++i) {
    int gr = r0 + ty * 4 + i;
    if (gr < N) {
      union { __half2 h[2]; float2 f; } u;
      u.h[0] = __float22half2_rn(make_float2(accs[i].x, accs[i].y));
      u.h[1] = __float22half2_rn(make_float2(accs[i].z, accs[i].w));
      *(float2*)(hL2 + (size_t)gr * 32 + tx * 4) = u.f;
    }
  }

  float4 asv = *(const float4*)(a_src + tx * 4);
  float4 adv = *(const float4*)(a_dst + tx * 4);
  float esp[4], edp[4];
#pragma unroll
  for (int i = 0; i < 4; ++i) {
    esp[i] = accs[i].x * asv.x + accs[i].y * asv.y + accs[i].z * asv.z + accs[i].w * asv.w;
    edp[i] = accs[i].x * adv.x + accs[i].y * adv.y + accs[i].z * adv.z + accs[i].w * adv.w;
  }
#pragma unroll
  for (int off = 1; off <= 4; off <<= 1) {
#pragma unroll
    for (int i = 0; i < 4; ++i) {
      esp[i] += __shfl_xor(esp[i], off);
      edp[i] += __shfl_xor(edp[i], off);
    }
  }
  if (tx == 0) {
#pragma unroll
    for (int i = 0; i < 4; ++i) {
      int gr = r0 + ty * 4 + i;
      if (gr < N) {
        es[gr] = esp[i];
        ed[gr] = edp[i];
      }
    }
  }
}

// -------- agg layer 2: one wave per dst; 16 groups x 4 lanes --------
__global__ __launch_bounds__(256) void k_agg2(const int* __restrict__ rowbeg,
                                              const int* __restrict__ rowend,
                                              const unsigned short* __restrict__ col,
                                              const __half* __restrict__ hL2,
                                              const float* __restrict__ es,
                                              const float* __restrict__ ed,
                                              const float* __restrict__ bias,
                                              float* __restrict__ out, int N) {
  int d = (blockIdx.x * blockDim.x + threadIdx.x) >> 6;
  int lane = threadIdx.x & 63;
  if (d >= N) return;
  int g = lane >> 2;   // edge group 0..15
  int q = lane & 3;    // channel octet 0..3
  int ch = q * 8;
  float edv = ed[d];

  float a0 = 0.f, a1 = 0.f, a2 = 0.f, a3 = 0.f, a4 = 0.f, a5 = 0.f, a6 = 0.f, a7 = 0.f;
  float wsum = 0.f;

  if (g == 0) {
    float v = es[d] + edv;
    v = v > 0.f ? v : NEG_SLOPE * v;
    float w = __expf(v);
    float4 raw = *(const float4*)(hL2 + (size_t)d * 32 + ch);
    const __half2* p2 = (const __half2*)&raw;
    float2 f0 = __half22float2(p2[0]), f1 = __half22float2(p2[1]);
    float2 f2 = __half22float2(p2[2]), f3 = __half22float2(p2[3]);
    a0 = w * f0.x; a1 = w * f0.y; a2 = w * f1.x; a3 = w * f1.y;
    a4 = w * f2.x; a5 = w * f2.y; a6 = w * f3.x; a7 = w * f3.y;
    wsum = w;
  }

  int beg = rowbeg[d], end = rowend[d];
  for (int j = beg + g; j < end; j += 16) {
    int s = col[j];
    float vv = es[s] + edv;
    vv = vv > 0.f ? vv : NEG_SLOPE * vv;
    float w = __expf(vv);
    float4 raw = *(const float4*)(hL2 + (size_t)s * 32 + ch);
    const __half2* p2 = (const __half2*)&raw;
    float2 f0 = __half22float2(p2[0]), f1 = __half22float2(p2[1]);
    float2 f2 = __half22float2(p2[2]), f3 = __half22float2(p2[3]);
    a0 += w * f0.x; a1 += w * f0.y; a2 += w * f1.x; a3 += w * f1.y;
    a4 += w * f2.x; a5 += w * f2.y; a6 += w * f3.x; a7 += w * f3.y;
    wsum += w;
  }

#pragma unroll
  for (int off = 4; off <= 32; off <<= 1) {
    a0 += __shfl_xor(a0, off); a1 += __shfl_xor(a1, off);
    a2 += __shfl_xor(a2, off); a3 += __shfl_xor(a3, off);
    a4 += __shfl_xor(a4, off); a5 += __shfl_xor(a5, off);
    a6 += __shfl_xor(a6, off); a7 += __shfl_xor(a7, off);
    wsum += __shfl_xor(wsum, off);
  }

  if (g == 0) {
    float inv = 1.f / (wsum + 1e-16f);
    const float4 bv0 = *(const float4*)(bias + ch);
    const float4 bv1 = *(const float4*)(bias + ch + 4);
    float4 o0, o1;
    o0.x = a0 * inv + bv0.x; o0.y = a1 * inv + bv0.y;
    o0.z = a2 * inv + bv0.z; o0.w = a3 * inv + bv0.w;
    o1.x = a4 * inv + bv1.x; o1.y = a5 * inv + bv1.y;
    o1.z = a6 * inv + bv1.z; o1.w = a7 * inv + bv1.w;
    *(float4*)(out + (size_t)d * 32 + ch) = o0;
    *(float4*)(out + (size_t)d * 32 + ch + 4) = o1;
  }
}

extern "C" void kernel_launch(void* const* d_in, const int* in_sizes, int n_in,
                              void* d_out, int out_size, void* d_ws, size_t ws_size,
                              hipStream_t stream) {
  const float* x      = (const float*)d_in[0];
  const int*   ei     = (const int*)d_in[1];
  const float* W1     = (const float*)d_in[2];
  const float* a_src1 = (const float*)d_in[3];
  const float* a_dst1 = (const float*)d_in[4];
  const float* b1     = (const float*)d_in[5];
  const float* W2     = (const float*)d_in[6];
  const float* a_src2 = (const float*)d_in[7];
  const float* a_dst2 = (const float*)d_in[8];
  const float* b2     = (const float*)d_in[9];
  float* out = (float*)d_out;

  const int N = in_sizes[0] / 128;
  const int E = in_sizes[1] / 2;
  const int NB = (N + DB - 1) / DB;
  const int* srcv = ei;
  const int* dstv = ei + E;

  char* base = (char*)d_ws;
  size_t off = 0;
  auto carve = [&](size_t bytes) {
    void* p = base + off;
    off += (bytes + 15) & ~(size_t)15;
    return p;
  };
  __half* h1     = (__half*)carve((size_t)N * 64 * 2);
  float*  es1    = (float*)carve((size_t)N * 2 * 4);
  float*  ed1    = (float*)carve((size_t)N * 2 * 4);
  float*  out1   = (float*)carve((size_t)N * 64 * 4);
  __half* hL2    = (__half*)carve((size_t)N * 32 * 2);
  float*  es2    = (float*)carve((size_t)N * 4);
  float*  ed2    = (float*)carve((size_t)N * 4);
  int*    gcur   = (int*)carve((size_t)NB_MAX * 4);
  int*    rowbeg = (int*)carve((size_t)N * 4);
  int*    rowend = (int*)carve((size_t)N * 4);
  unsigned short* col = (unsigned short*)carve((size_t)NB * CAP * 2);
  int*    ebuf   = (int*)carve((size_t)NB * CAP * 4);

  const int pblocks = (E + EPB - 1) / EPB;
  const int G1 = (N + 63) / 64;

  hipMemsetAsync(gcur, 0, (size_t)NB_MAX * sizeof(int), stream);

  // ---- gemm1+scores1 ∥ edge partition (independent) ----
  k_g1p<<<G1 + pblocks, 256, 0, stream>>>(x, W1, a_src1, a_dst1, h1, es1, ed1, N,
                                          srcv, dstv, gcur, ebuf, E, G1);
  // ---- per-bucket CSR finalize ----
  k_csr<<<NB, 256, 0, stream>>>(gcur, ebuf, rowbeg, rowend, col, N);

  // ---- layer-1 aggregate ----
  k_agg1<<<((size_t)N * 64 + 255) / 256, 256, 0, stream>>>(rowbeg, rowend, col, h1, es1, ed1, b1, out1, N);

  // ---- layer 2 ----
  k_gemm2<<<(N + 127) / 128, 256, 0, stream>>>(out1, W2, a_src2, a_dst2, hL2, es2, ed2, N);
  k_agg2<<<((size_t)N * 64 + 255) / 256, 256, 0, stream>>>(rowbeg, rowend, col, hL2, es2, ed2, b2, out, N);
}

// Round 10
// 202.439 us; speedup vs baseline: 1.0707x; 1.0381x over previous
//
#include <hip/hip_runtime.h>
#include <hip/hip_fp16.h>

#define NEG_SLOPE 0.2f
#define DB 128       // dst nodes per bucket
#define NB_MAX 512   // max buckets (N <= 65536)
#define EPB 4096     // edges per block in partition path
#define CAP 8192     // fixed capacity per bucket segment (mean load ~4092)

// ============ merged: GEMM1+scores1 (blocks [0,G1)) ∥ edge partition (rest) ============
// GEMM tile M=128,N=64,K=128; fp16 LDS staging (48 KB total) => 3 blocks/CU.
__global__ __launch_bounds__(256) void k_g1p(
    const float* __restrict__ x, const float* __restrict__ W,
    const float* __restrict__ a_src, const float* __restrict__ a_dst,
    __half* __restrict__ h1, float* __restrict__ es, float* __restrict__ ed, int N,
    const int* __restrict__ srcv, const int* __restrict__ dstv,
    int* __restrict__ gcur, int* __restrict__ ebuf, int E, int G1) {
  __shared__ __align__(16) char smem[49152];
  const int t = threadIdx.x;

  if ((int)blockIdx.x < G1) {
    // ---------------- GEMM1 + fused scores1 (fp16 LDS, fp32 accumulate) ----------------
    __half* sXT = (__half*)smem;            // [k][row] 128x128 halves, 32 KB
    __half* sW  = (__half*)(smem + 32768);  // [k][col] 128x64 halves, 16 KB
    const int r0 = blockIdx.x * 128;

    {  // stage W1 (k-major already): 32 floats/thread
      const float4* Wp = (const float4*)W;
#pragma unroll
      for (int i = 0; i < 8; ++i) {
        float4 v = Wp[t + i * 256];
        int fi = (t + i * 256) * 4;
        union { __half2 h2[2]; float2 f; } u;
        u.h2[0] = __float22half2_rn(make_float2(v.x, v.y));
        u.h2[1] = __float22half2_rn(make_float2(v.z, v.w));
        *(float2*)(sW + fi) = u.f;
      }
    }
    {  // stage x transposed: thread -> row r=t&127, k-half (t>>7)*64
      int r = t & 127;
      int kb = (t >> 7) * 64;
      int gr = r0 + r;
      bool ok = gr < N;
      const float* xr = x + (size_t)gr * 128 + kb;
#pragma unroll
      for (int p = 0; p < 16; ++p) {
        int k = kb + p * 4;
        float4 v = ok ? *(const float4*)(xr + p * 4) : make_float4(0.f, 0.f, 0.f, 0.f);
        sXT[(k + 0) * 128 + r] = __float2half(v.x);
        sXT[(k + 1) * 128 + r] = __float2half(v.y);
        sXT[(k + 2) * 128 + r] = __float2half(v.z);
        sXT[(k + 3) * 128 + r] = __float2half(v.w);
      }
    }
    __syncthreads();

    const int tx = t & 15, ty = t >> 4;  // 4 cols x 8 rows per thread
    float4 acc[8];
#pragma unroll
    for (int i = 0; i < 8; ++i) acc[i] = make_float4(0.f, 0.f, 0.f, 0.f);

#pragma unroll 4
    for (int k = 0; k < 128; ++k) {
      float4 araw = *(const float4*)(sXT + k * 128 + ty * 8);  // 8 halves
      float2 braw = *(const float2*)(sW + k * 64 + tx * 4);    // 4 halves
      const __half2* ah = (const __half2*)&araw;
      const __half2* bh = (const __half2*)&braw;
      float2 b01 = __half22float2(bh[0]);
      float2 b23 = __half22float2(bh[1]);
      float av[8];
#pragma unroll
      for (int h = 0; h < 4; ++h) {
        float2 f = __half22float2(ah[h]);
        av[h * 2] = f.x; av[h * 2 + 1] = f.y;
      }
#pragma unroll
      for (int i = 0; i < 8; ++i) {
        acc[i].x += av[i] * b01.x;
        acc[i].y += av[i] * b01.y;
        acc[i].z += av[i] * b23.x;
        acc[i].w += av[i] * b23.y;
      }
    }

#pragma unroll
    for (int i = 0; i < 8; ++i) {
      int gr = r0 + ty * 8 + i;
      if (gr < N) {
        union { __half2 h[2]; float2 f; } u;
        u.h[0] = __float22half2_rn(make_float2(acc[i].x, acc[i].y));
        u.h[1] = __float22half2_rn(make_float2(acc[i].z, acc[i].w));
        *(float2*)(h1 + (size_t)gr * 64 + tx * 4) = u.f;
      }
    }

    float4 asv = *(const float4*)(a_src + tx * 4);
    float4 adv = *(const float4*)(a_dst + tx * 4);
    float esp[8], edp[8];
#pragma unroll
    for (int i = 0; i < 8; ++i) {
      esp[i] = acc[i].x * asv.x + acc[i].y * asv.y + acc[i].z * asv.z + acc[i].w * asv.w;
      edp[i] = acc[i].x * adv.x + acc[i].y * adv.y + acc[i].z * adv.z + acc[i].w * adv.w;
    }
#pragma unroll
    for (int off = 1; off <= 4; off <<= 1) {
#pragma unroll
      for (int i = 0; i < 8; ++i) {
        esp[i] += __shfl_xor(esp[i], off);
        edp[i] += __shfl_xor(edp[i], off);
      }
    }
    if ((tx & 7) == 0) {
      int hh = tx >> 3;
#pragma unroll
      for (int i = 0; i < 8; ++i) {
        int gr = r0 + ty * 8 + i;
        if (gr < N) {
          es[gr * 2 + hh] = esp[i];
          ed[gr * 2 + hh] = edp[i];
        }
      }
    }
  } else {
    // ---------------- edge partition into fixed-cap bucket segments ----------------
    int* sh    = (int*)smem;           // 512 ints
    int* lbase = (int*)(smem + 2048);  // 512 ints
    sh[t] = 0; sh[t + 256] = 0;
    __syncthreads();
    int base = (blockIdx.x - G1) * EPB;
    int dd[16];
#pragma unroll
    for (int i = 0; i < 16; ++i) {
      int e = base + i * 256 + t;
      dd[i] = (e < E) ? dstv[e] : -1;
      if (dd[i] >= 0) atomicAdd(&sh[dd[i] >> 7], 1);
    }
    __syncthreads();
#pragma unroll
    for (int i = 0; i < 2; ++i) {
      int b = t + 256 * i;
      int c = sh[b];
      lbase[b] = c ? (b * CAP + atomicAdd(&gcur[b], c)) : 0;
      sh[b] = 0;  // becomes local cursor
    }
    __syncthreads();
#pragma unroll
    for (int i = 0; i < 16; ++i) {
      if (dd[i] >= 0) {
        int e = base + i * 256 + t;
        int b = dd[i] >> 7;
        int r = atomicAdd(&sh[b], 1);
        ebuf[lbase[b] + r] = srcv[e] | ((dd[i] & 127) << 16);
      }
    }
  }
}

// Phase 2: per-bucket local counting sort -> rowbeg/rowend + col(u16)
__global__ __launch_bounds__(256) void k_csr(const int* __restrict__ gcur,
                                             const int* __restrict__ ebuf,
                                             int* __restrict__ rowbeg,
                                             int* __restrict__ rowend,
                                             unsigned short* __restrict__ col, int N) {
  int b = blockIdx.x;
  int cnt = gcur[b];
  int base = b * CAP;
  int dbase = b * DB;
  __shared__ int dh[DB];
  __shared__ int sc[DB];
  int t = threadIdx.x;
  if (t < DB) dh[t] = 0;
  __syncthreads();
  for (int j = t; j < cnt; j += 256) {
    int p = ebuf[base + j];
    atomicAdd(&dh[p >> 16], 1);
  }
  __syncthreads();
  int v = 0;
  if (t < DB) { v = dh[t]; sc[t] = v; }
  __syncthreads();
  for (int off = 1; off < DB; off <<= 1) {
    int u = 0;
    if (t < DB && t >= off) u = sc[t - off];
    __syncthreads();
    if (t < DB) sc[t] += u;
    __syncthreads();
  }
  if (t < DB) {
    int excl = sc[t] - v;
    int d = dbase + t;
    if (d < N) {
      rowbeg[d] = base + excl;
      rowend[d] = base + excl + v;
    }
    dh[t] = base + excl;
  }
  __syncthreads();
  for (int j = t; j < cnt; j += 256) {
    int p = ebuf[base + j];
    int r = atomicAdd(&dh[p >> 16], 1);
    col[r] = (unsigned short)(p & 0xFFFF);
  }
}

// -------- agg layer 1: one wave per dst; 8 groups x 8 lanes; unrolled for MLP --------
__global__ __launch_bounds__(256) void k_agg1(const int* __restrict__ rowbeg,
                                              const int* __restrict__ rowend,
                                              const unsigned short* __restrict__ col,
                                              const __half* __restrict__ h1,
                                              const float* __restrict__ es,
                                              const float* __restrict__ ed,
                                              const float* __restrict__ bias,
                                              float* __restrict__ out1, int N) {
  int d = (blockIdx.x * blockDim.x + threadIdx.x) >> 6;
  int lane = threadIdx.x & 63;
  if (d >= N) return;
  int g = lane >> 3;   // edge group 0..7
  int q = lane & 7;    // channel octet 0..7
  int ch = q * 8;
  int hh = q >> 2;     // head
  float edv = ed[d * 2 + hh];

  float a0 = 0.f, a1 = 0.f, a2 = 0.f, a3 = 0.f, a4 = 0.f, a5 = 0.f, a6 = 0.f, a7 = 0.f;
  float wsum = 0.f;

  if (g == 0) {  // self-loop
    float v = es[d * 2 + hh] + edv;
    v = v > 0.f ? v : NEG_SLOPE * v;
    float w = __expf(v);
    float4 raw = *(const float4*)(h1 + (size_t)d * 64 + ch);
    const __half2* p2 = (const __half2*)&raw;
    float2 f0 = __half22float2(p2[0]), f1 = __half22float2(p2[1]);
    float2 f2 = __half22float2(p2[2]), f3 = __half22float2(p2[3]);
    a0 = w * f0.x; a1 = w * f0.y; a2 = w * f1.x; a3 = w * f1.y;
    a4 = w * f2.x; a5 = w * f2.y; a6 = w * f3.x; a7 = w * f3.y;
    wsum = w;
  }

  int beg = rowbeg[d], end = rowend[d];
#pragma unroll 2
  for (int j = beg + g; j < end; j += 8) {
    int s = col[j];
    float vv = es[s * 2 + hh] + edv;
    vv = vv > 0.f ? vv : NEG_SLOPE * vv;
    float w = __expf(vv);
    float4 raw = *(const float4*)(h1 + (size_t)s * 64 + ch);
    const __half2* p2 = (const __half2*)&raw;
    float2 f0 = __half22float2(p2[0]), f1 = __half22float2(p2[1]);
    float2 f2 = __half22float2(p2[2]), f3 = __half22float2(p2[3]);
    a0 += w * f0.x; a1 += w * f0.y; a2 += w * f1.x; a3 += w * f1.y;
    a4 += w * f2.x; a5 += w * f2.y; a6 += w * f3.x; a7 += w * f3.y;
    wsum += w;
  }

#pragma unroll
  for (int off = 8; off <= 32; off <<= 1) {
    a0 += __shfl_xor(a0, off); a1 += __shfl_xor(a1, off);
    a2 += __shfl_xor(a2, off); a3 += __shfl_xor(a3, off);
    a4 += __shfl_xor(a4, off); a5 += __shfl_xor(a5, off);
    a6 += __shfl_xor(a6, off); a7 += __shfl_xor(a7, off);
    wsum += __shfl_xor(wsum, off);
  }

  if (g == 0) {
    float inv = 1.f / (wsum + 1e-16f);
    const float4 bv0 = *(const float4*)(bias + ch);
    const float4 bv1 = *(const float4*)(bias + ch + 4);
    float4 o0, o1;
    o0.x = a0 * inv + bv0.x; o0.y = a1 * inv + bv0.y;
    o0.z = a2 * inv + bv0.z; o0.w = a3 * inv + bv0.w;
    o1.x = a4 * inv + bv1.x; o1.y = a5 * inv + bv1.y;
    o1.z = a6 * inv + bv1.z; o1.w = a7 * inv + bv1.w;
    *(float4*)(out1 + (size_t)d * 64 + ch) = o0;
    *(float4*)(out1 + (size_t)d * 64 + ch + 4) = o1;
  }
}

// ======== GEMM2 + fused scores2: hL2(fp16) = relu(out1)@W2 ; es2/ed2 ========
__global__ __launch_bounds__(256) void k_gemm2(const float* __restrict__ out1,
                                               const float* __restrict__ W,
                                               const float* __restrict__ a_src,
                                               const float* __restrict__ a_dst,
                                               __half* __restrict__ hL2,
                                               float* __restrict__ es,
                                               float* __restrict__ ed, int N) {
  __shared__ float sXT[64 * 128];
  __shared__ float sW[64 * 32];
  const int t = threadIdx.x;
  const int r0 = blockIdx.x * 128;

  {
    const float4* Wp = (const float4*)W;
    float4* sWp = (float4*)sW;
#pragma unroll
    for (int i = 0; i < 2; ++i) sWp[t + i * 256] = Wp[t + i * 256];
  }
  {
    int r = t & 127;
    int kq = t >> 7;
    int gr = r0 + r;
    bool ok = gr < N;
    const float* xr = out1 + (size_t)gr * 64;
#pragma unroll
    for (int p = 0; p < 8; ++p) {
      int k = (kq + p * 2) * 4;
      float4 v = ok ? *(const float4*)(xr + k) : make_float4(0.f, 0.f, 0.f, 0.f);
      sXT[(k + 0) * 128 + r] = fmaxf(v.x, 0.f);
      sXT[(k + 1) * 128 + r] = fmaxf(v.y, 0.f);
      sXT[(k + 2) * 128 + r] = fmaxf(v.z, 0.f);
      sXT[(k + 3) * 128 + r] = fmaxf(v.w, 0.f);
    }
  }
  __syncthreads();

  const int tx = t & 7, ty = t >> 3;
  float4 acc0 = make_float4(0.f, 0.f, 0.f, 0.f);
  float4 acc1 = acc0, acc2 = acc0, acc3 = acc0;
#pragma unroll 8
  for (int k = 0; k < 64; ++k) {
    float4 av = *(const float4*)(sXT + k * 128 + ty * 4);
    float4 bv = *(const float4*)(sW + k * 32 + tx * 4);
    acc0.x += av.x * bv.x; acc0.y += av.x * bv.y; acc0.z += av.x * bv.z; acc0.w += av.x * bv.w;
    acc1.x += av.y * bv.x; acc1.y += av.y * bv.y; acc1.z += av.y * bv.z; acc1.w += av.y * bv.w;
    acc2.x += av.z * bv.x; acc2.y += av.z * bv.y; acc2.z += av.z * bv.z; acc2.w += av.z * bv.w;
    acc3.x += av.w * bv.x; acc3.y += av.w * bv.y; acc3.z += av.w * bv.z; acc3.w += av.w * bv.w;
  }

  float4 accs[4] = {acc0, acc1, acc2, acc3};
#pragma unroll
  for (int i = 0; i < 4; ++i) {
    int gr = r0 + ty * 4 + i;
    if (gr < N) {
      union { __half2 h[2]; float2 f; } u;
      u.h[0] = __float22half2_rn(make_float2(accs[i].x, accs[i].y));
      u.h[1] = __float22half2_rn(make_float2(accs[i].z, accs[i].w));
      *(float2*)(hL2 + (size_t)gr * 32 + tx * 4) = u.f;
    }
  }

  float4 asv = *(const float4*)(a_src + tx * 4);
  float4 adv = *(const float4*)(a_dst + tx * 4);
  float esp[4], edp[4];
#pragma unroll
  for (int i = 0; i < 4; ++i) {
    esp[i] = accs[i].x * asv.x + accs[i].y * asv.y + accs[i].z * asv.z + accs[i].w * asv.w;
    edp[i] = accs[i].x * adv.x + accs[i].y * adv.y + accs[i].z * adv.z + accs[i].w * adv.w;
  }
#pragma unroll
  for (int off = 1; off <= 4; off <<= 1) {
#pragma unroll
    for (int i = 0; i < 4; ++i) {
      esp[i] += __shfl_xor(esp[i], off);
      edp[i] += __shfl_xor(edp[i], off);
    }
  }
  if (tx == 0) {
#pragma unroll
    for (int i = 0; i < 4; ++i) {
      int gr = r0 + ty * 4 + i;
      if (gr < N) {
        es[gr] = esp[i];
        ed[gr] = edp[i];
      }
    }
  }
}

// -------- agg layer 2: one wave per dst; 16 groups x 4 lanes; unrolled --------
__global__ __launch_bounds__(256) void k_agg2(const int* __restrict__ rowbeg,
                                              const int* __restrict__ rowend,
                                              const unsigned short* __restrict__ col,
                                              const __half* __restrict__ hL2,
                                              const float* __restrict__ es,
                                              const float* __restrict__ ed,
                                              const float* __restrict__ bias,
                                              float* __restrict__ out, int N) {
  int d = (blockIdx.x * blockDim.x + threadIdx.x) >> 6;
  int lane = threadIdx.x & 63;
  if (d >= N) return;
  int g = lane >> 2;   // edge group 0..15
  int q = lane & 3;    // channel octet 0..3
  int ch = q * 8;
  float edv = ed[d];

  float a0 = 0.f, a1 = 0.f, a2 = 0.f, a3 = 0.f, a4 = 0.f, a5 = 0.f, a6 = 0.f, a7 = 0.f;
  float wsum = 0.f;

  if (g == 0) {
    float v = es[d] + edv;
    v = v > 0.f ? v : NEG_SLOPE * v;
    float w = __expf(v);
    float4 raw = *(const float4*)(hL2 + (size_t)d * 32 + ch);
    const __half2* p2 = (const __half2*)&raw;
    float2 f0 = __half22float2(p2[0]), f1 = __half22float2(p2[1]);
    float2 f2 = __half22float2(p2[2]), f3 = __half22float2(p2[3]);
    a0 = w * f0.x; a1 = w * f0.y; a2 = w * f1.x; a3 = w * f1.y;
    a4 = w * f2.x; a5 = w * f2.y; a6 = w * f3.x; a7 = w * f3.y;
    wsum = w;
  }

  int beg = rowbeg[d], end = rowend[d];
#pragma unroll 2
  for (int j = beg + g; j < end; j += 16) {
    int s = col[j];
    float vv = es[s] + edv;
    vv = vv > 0.f ? vv : NEG_SLOPE * vv;
    float w = __expf(vv);
    float4 raw = *(const float4*)(hL2 + (size_t)s * 32 + ch);
    const __half2* p2 = (const __half2*)&raw;
    float2 f0 = __half22float2(p2[0]), f1 = __half22float2(p2[1]);
    float2 f2 = __half22float2(p2[2]), f3 = __half22float2(p2[3]);
    a0 += w * f0.x; a1 += w * f0.y; a2 += w * f1.x; a3 += w * f1.y;
    a4 += w * f2.x; a5 += w * f2.y; a6 += w * f3.x; a7 += w * f3.y;
    wsum += w;
  }

#pragma unroll
  for (int off = 4; off <= 32; off <<= 1) {
    a0 += __shfl_xor(a0, off); a1 += __shfl_xor(a1, off);
    a2 += __shfl_xor(a2, off); a3 += __shfl_xor(a3, off);
    a4 += __shfl_xor(a4, off); a5 += __shfl_xor(a5, off);
    a6 += __shfl_xor(a6, off); a7 += __shfl_xor(a7, off);
    wsum += __shfl_xor(wsum, off);
  }

  if (g == 0) {
    float inv = 1.f / (wsum + 1e-16f);
    const float4 bv0 = *(const float4*)(bias + ch);
    const float4 bv1 = *(const float4*)(bias + ch + 4);
    float4 o0, o1;
    o0.x = a0 * inv + bv0.x; o0.y = a1 * inv + bv0.y;
    o0.z = a2 * inv + bv0.z; o0.w = a3 * inv + bv0.w;
    o1.x = a4 * inv + bv1.x; o1.y = a5 * inv + bv1.y;
    o1.z = a6 * inv + bv1.z; o1.w = a7 * inv + bv1.w;
    *(float4*)(out + (size_t)d * 32 + ch) = o0;
    *(float4*)(out + (size_t)d * 32 + ch + 4) = o1;
  }
}

extern "C" void kernel_launch(void* const* d_in, const int* in_sizes, int n_in,
                              void* d_out, int out_size, void* d_ws, size_t ws_size,
                              hipStream_t stream) {
  const float* x      = (const float*)d_in[0];
  const int*   ei     = (const int*)d_in[1];
  const float* W1     = (const float*)d_in[2];
  const float* a_src1 = (const float*)d_in[3];
  const float* a_dst1 = (const float*)d_in[4];
  const float* b1     = (const float*)d_in[5];
  const float* W2     = (const float*)d_in[6];
  const float* a_src2 = (const float*)d_in[7];
  const float* a_dst2 = (const float*)d_in[8];
  const float* b2     = (const float*)d_in[9];
  float* out = (float*)d_out;

  const int N = in_sizes[0] / 128;
  const int E = in_sizes[1] / 2;
  const int NB = (N + DB - 1) / DB;
  const int* srcv = ei;
  const int* dstv = ei + E;

  char* base = (char*)d_ws;
  size_t off = 0;
  auto carve = [&](size_t bytes) {
    void* p = base + off;
    off += (bytes + 15) & ~(size_t)15;
    return p;
  };
  __half* h1     = (__half*)carve((size_t)N * 64 * 2);
  float*  es1    = (float*)carve((size_t)N * 2 * 4);
  float*  ed1    = (float*)carve((size_t)N * 2 * 4);
  float*  out1   = (float*)carve((size_t)N * 64 * 4);
  __half* hL2    = (__half*)carve((size_t)N * 32 * 2);
  float*  es2    = (float*)carve((size_t)N * 4);
  float*  ed2    = (float*)carve((size_t)N * 4);
  int*    gcur   = (int*)carve((size_t)NB_MAX * 4);
  int*    rowbeg = (int*)carve((size_t)N * 4);
  int*    rowend = (int*)carve((size_t)N * 4);
  unsigned short* col = (unsigned short*)carve((size_t)NB * CAP * 2);
  int*    ebuf   = (int*)carve((size_t)NB * CAP * 4);

  const int pblocks = (E + EPB - 1) / EPB;
  const int G1 = (N + 127) / 128;

  hipMemsetAsync(gcur, 0, (size_t)NB_MAX * sizeof(int), stream);

  // ---- gemm1+scores1 ∥ edge partition (independent) ----
  k_g1p<<<G1 + pblocks, 256, 0, stream>>>(x, W1, a_src1, a_dst1, h1, es1, ed1, N,
                                          srcv, dstv, gcur, ebuf, E, G1);
  // ---- per-bucket CSR finalize ----
  k_csr<<<NB, 256, 0, stream>>>(gcur, ebuf, rowbeg, rowend, col, N);

  // ---- layer-1 aggregate ----
  k_agg1<<<((size_t)N * 64 + 255) / 256, 256, 0, stream>>>(rowbeg, rowend, col, h1, es1, ed1, b1, out1, N);

  // ---- layer 2 ----
  k_gemm2<<<(N + 127) / 128, 256, 0, stream>>>(out1, W2, a_src2, a_dst2, hL2, es2, ed2, N);
  k_agg2<<<((size_t)N * 64 + 255) / 256, 256, 0, stream>>>(rowbeg, rowend, col, hL2, es2, ed2, b2, out, N);
}